// Round 17
// baseline (355.720 us; speedup 1.0000x reference)
//
#include <hip/hip_runtime.h>
#include <hip/hip_bf16.h>
#include <cstdint>

static constexpr int S   = 1024;
static constexpr int H   = 2048;
static constexpr int NH  = 16;
static constexpr int NKV = 4;
static constexpr int HD  = 128;
static constexpr int EXPN = 8;
static constexpr int FFI = 1024;

typedef __bf16 bf16x8 __attribute__((ext_vector_type(8)));
typedef float  f32x4  __attribute__((ext_vector_type(4)));
typedef unsigned short ushortx8 __attribute__((ext_vector_type(8)));
typedef unsigned short ushortx4 __attribute__((ext_vector_type(4)));

#define DEVI __device__ __forceinline__

DEVI unsigned short f2bf(float f) {
    union { float f; uint32_t u; } v; v.f = f;
    uint32_t r = (v.u + 0x7FFFu + ((v.u >> 16) & 1u)) >> 16;
    return (unsigned short)r;
}
DEVI float bf2f(unsigned short s) {
    union { uint32_t u; float f; } v; v.u = ((uint32_t)s) << 16; return v.f;
}

DEVI void atomAdd(float* p, float v) { unsafeAtomicAdd(p, v); }

// async global->LDS, 16B per lane; dest is wave-uniform base + lane*16
DEVI void gll16(const unsigned short* g, unsigned short* l) {
    __builtin_amdgcn_global_load_lds(
        (const __attribute__((address_space(1))) unsigned int*)(g),
        (__attribute__((address_space(3))) unsigned int*)(l),
        16, 0, 0);
}

// counted vmcnt wait (vm only)
template<int N> DEVI void waitvm() {
    if constexpr (N == 0)      asm volatile("s_waitcnt vmcnt(0)" ::: "memory");
    else if constexpr (N == 2) asm volatile("s_waitcnt vmcnt(2)" ::: "memory");
    else if constexpr (N == 4) asm volatile("s_waitcnt vmcnt(4)" ::: "memory");
    else if constexpr (N == 6) asm volatile("s_waitcnt vmcnt(6)" ::: "memory");
    else static_assert(N == 0 || N == 2 || N == 4 || N == 6, "unsupported vmcnt");
}
DEVI void pipe_barrier() {
    __builtin_amdgcn_sched_barrier(0);
    __builtin_amdgcn_s_barrier();
    __builtin_amdgcn_sched_barrier(0);
}

// ---------------------------------------------------------------------------
// Tiled transpose + fp32->bf16 convert:  in fp32 [R][C] -> out bf16 [C][R]
// ---------------------------------------------------------------------------
__global__ __launch_bounds__(256) void transT(const float* __restrict__ in,
                                              unsigned short* __restrict__ outp,
                                              int R, int C)
{
    __shared__ unsigned short tl[64][72];
    int zb = blockIdx.z;
    in   += (size_t)zb * R * C;
    outp += (size_t)zb * R * C;
    int c0 = blockIdx.x * 64, r0 = blockIdx.y * 64;
    int t = threadIdx.x;
    int cq = (t & 15) * 4;
    int rr = t >> 4;
    #pragma unroll
    for (int p = 0; p < 4; ++p) {
        int row = rr + p * 16;
        float4 v = *(const float4*)&in[(size_t)(r0 + row) * C + c0 + cq];
        tl[cq + 0][row] = f2bf(v.x);
        tl[cq + 1][row] = f2bf(v.y);
        tl[cq + 2][row] = f2bf(v.z);
        tl[cq + 3][row] = f2bf(v.w);
    }
    __syncthreads();
    int r8 = (t & 7) * 8;
    int cc = t >> 3;
    #pragma unroll
    for (int p = 0; p < 2; ++p) {
        int col = cc + p * 32;
        ushortx8 v = *(const ushortx8*)&tl[col][r8];
        *(ushortx8*)&outp[(size_t)(c0 + col) * R + r0 + r8] = v;
    }
}

enum { CFG_PROJ3 = 0, CFG_WO = 1, CFG_SCORES = 2, CFG_PV = 3, CFG_GATEUP = 4, CFG_DOWN = 5 };

// ---------------------------------------------------------------------------
// BMxBN MFMA GEMM tile (BM=WM*32, BN=NI*32), 4 waves (2x2), BK=64.
// PIPE=false: 2-buffer LDS + __syncthreads.
// PIPE=true : 3-buffer LDS, 2 tiles in flight, counted vmcnt.
// GATEUP: A-fragments loaded per-lane from global (L2-resident tbf), LDS holds
// only B/B2 -> 48 KB 3-buffer pipeline fits 3 blocks/CU.
// A bf16 [M][LDA], B bf16 [N][LDBK] (pre-transposed).
// ---------------------------------------------------------------------------
template<int CFG, int WM, int NI, bool PIPE>
__global__ __launch_bounds__(256, 2) void gemm_k(
    const unsigned short* __restrict__ A,
    const unsigned short* __restrict__ B0,
    const unsigned short* __restrict__ B1,
    const unsigned short* __restrict__ B2,
    float* __restrict__ C0,
    float* __restrict__ C1,
    float* __restrict__ C2,
    unsigned short* __restrict__ Cb,
    const float* __restrict__ X,
    const int* __restrict__ cnt,
    const int* __restrict__ tokList,
    int arg0)
{
    constexpr bool DUAL = (CFG == CFG_GATEUP);
    constexpr bool AREG = (CFG == CFG_GATEUP);   // A direct-to-register
    constexpr int BM = WM * 32;
    constexpr int BN = NI * 32;
    constexpr int ASZ = BM * 64;
    constexpr int BSZ = BN * 64;
    constexpr int NBUF = PIPE ? 3 : 2;
    constexpr int LD = AREG ? (2 * NI) : (WM + NI + (DUAL ? NI : 0));

    const int tid = threadIdx.x;
    const int m0 = blockIdx.y * BM;
    int n0 = blockIdx.x * BN;

    int M = S;
    int kbeg = 0, kend = 0, LDA = 0, LDBK = 0, LDC = 0;
    const unsigned short* Ap = A;
    const unsigned short* Bb = B0;
    const unsigned short* Bb2 = B1;
    const int* tlist = nullptr;
    float* Cout = C0;
    int head = 0, e = 0, hl = 0;

    if constexpr (CFG == CFG_PROJ3) {
        int xt = blockIdx.x;   // BN=64 tiling: q 32 tiles, k 8, v 8
        if (xt < 32)      { Bb = B0; Cout = C0; LDC = 2048; n0 = xt * 64; }
        else if (xt < 40) { Bb = B1; Cout = C1; LDC = 512;  n0 = (xt - 32) * 64; }
        else              { Bb = B2; Cout = C2; LDC = 512;  n0 = (xt - 40) * 64; }
        LDA = H; LDBK = H; kend = H;
    } else if constexpr (CFG == CFG_WO) {
        LDA = H; LDBK = H; LDC = H; kend = H;
    } else if constexpr (CFG == CFG_SCORES) {
        hl = blockIdx.z; head = arg0 + hl;
        if (n0 >= m0 + BM) return;
        Ap = A + (size_t)head * S * HD;
        Bb = B0 + (size_t)(head >> 2) * S * HD;
        kend = HD; LDA = HD; LDBK = HD;
    } else if constexpr (CFG == CFG_PV) {
        int z = blockIdx.z; hl = z >> 2; int ks = z & 3;
        head = arg0 + hl;
        int kcap = m0 + BM;
        kbeg = ks * 256;
        if (kbeg >= kcap) return;
        kend = (kbeg + 256 < kcap) ? kbeg + 256 : kcap;
        Ap = A + (size_t)hl * S * S;
        Bb = B0 + (size_t)(head >> 2) * HD * S;
        LDA = S; LDBK = S;
    } else if constexpr (CFG == CFG_GATEUP) {
        e = blockIdx.z;
        M = cnt[e]; if (m0 >= M) return;
        tlist = tokList + e * S;
        Bb  = B0 + (size_t)e * FFI * H;
        Bb2 = B1 + (size_t)e * FFI * H;
        kend = H; LDA = H; LDBK = H;
    } else { // CFG_DOWN
        e = blockIdx.z;
        M = cnt[e]; if (m0 >= M) return;
        Ap = A + (size_t)e * S * FFI;
        Bb = B0 + (size_t)e * H * FFI;
        kend = FFI; LDA = FFI; LDBK = FFI;
    }

    __shared__ unsigned short As[AREG ? 8 : NBUF * ASZ];
    __shared__ unsigned short Bs[NBUF * BSZ];
    __shared__ unsigned short Bs2[DUAL ? NBUF * BSZ : 8];

    const int lane = tid & 63, grp = lane >> 4, r16 = lane & 15;
    const int wid = tid >> 6, wr = wid >> 1, wc = wid & 1;
    const int wbase8 = (tid & 0xFFC0) * 8;   // wave-uniform LDS short-offset base

    // ---- precompute k-invariant per-thread source offsets ----
    size_t aoff[WM];
    const unsigned short* aptr[AREG ? WM : 1];
    if constexpr (AREG) {
        #pragma unroll
        for (int mi = 0; mi < WM; ++mi) {
            int row = wr * (WM * 16) + mi * 16 + r16;
            int gr = m0 + row; if (gr >= M) gr = M - 1;
            aptr[mi] = Ap + (size_t)tlist[gr] * LDA + grp * 8;
        }
    } else {
        #pragma unroll
        for (int c = 0; c < WM; ++c) {
            int chunk = c * 256 + tid;
            int row = chunk >> 3;
            int kcs = (chunk & 7) * 8;
            int grow = m0 + row;
            if constexpr (CFG == CFG_DOWN) { grow = grow < M ? grow : M - 1; }
            aoff[c] = (size_t)grow * LDA + (kcs ^ ((row & 7) << 3));
        }
    }
    size_t boff[NI];
    #pragma unroll
    for (int c = 0; c < NI; ++c) {
        int chunk = c * 256 + tid;
        int row = chunk >> 3;
        int kcs = (chunk & 7) * 8;
        boff[c] = (size_t)(n0 + row) * LDBK + (kcs ^ ((row & 7) << 3));
    }

    auto STAGE = [&](int buf, int k0) {
        if constexpr (!AREG) {
            #pragma unroll
            for (int c = 0; c < WM; ++c)
                gll16(Ap + aoff[c] + k0, &As[buf * ASZ + c * 2048 + wbase8]);
        }
        #pragma unroll
        for (int c = 0; c < NI; ++c)
            gll16(Bb + boff[c] + k0, &Bs[buf * BSZ + c * 2048 + wbase8]);
        if constexpr (DUAL) {
            #pragma unroll
            for (int c = 0; c < NI; ++c)
                gll16(Bb2 + boff[c] + k0, &Bs2[buf * BSZ + c * 2048 + wbase8]);
        }
    };

    f32x4 acc[WM][NI] = {};
    f32x4 acc2[DUAL ? WM : 1][DUAL ? NI : 1] = {};
    bf16x8 afg[AREG ? WM : 1][AREG ? 2 : 1];   // A fragments (AREG path)

    auto LOAD_A = [&](int k0) {
        if constexpr (AREG) {
            #pragma unroll
            for (int mi = 0; mi < WM; ++mi)
                #pragma unroll
                for (int t2 = 0; t2 < 2; ++t2)
                    afg[mi][t2] = __builtin_bit_cast(bf16x8, *(const ushortx8*)(aptr[mi] + k0 + t2 * 32));
        }
    };

    auto COMPUTE = [&](int buf) {
        #pragma unroll
        for (int kk = 0; kk < 64; kk += 32) {
            bf16x8 af[WM], bfr[NI], bfr2[DUAL ? NI : 1];
            #pragma unroll
            for (int mi = 0; mi < WM; ++mi) {
                if constexpr (AREG) {
                    af[mi] = afg[mi][kk >> 5];
                } else {
                    int r = wr * (WM * 16) + mi * 16 + r16;
                    int idx = buf * ASZ + r * 64 + ((kk + grp * 8) ^ ((r & 7) << 3));
                    af[mi] = __builtin_bit_cast(bf16x8, *(const ushortx8*)&As[idx]);
                }
            }
            #pragma unroll
            for (int ni = 0; ni < NI; ++ni) {
                int r = wc * (NI * 16) + ni * 16 + r16;
                int idx = buf * BSZ + r * 64 + ((kk + grp * 8) ^ ((r & 7) << 3));
                bfr[ni] = __builtin_bit_cast(bf16x8, *(const ushortx8*)&Bs[idx]);
                if constexpr (DUAL)
                    bfr2[ni] = __builtin_bit_cast(bf16x8, *(const ushortx8*)&Bs2[idx]);
            }
            #pragma unroll
            for (int mi = 0; mi < WM; ++mi)
                #pragma unroll
                for (int ni = 0; ni < NI; ++ni) {
                    acc[mi][ni] = __builtin_amdgcn_mfma_f32_16x16x32_bf16(af[mi], bfr[ni], acc[mi][ni], 0, 0, 0);
                    if constexpr (DUAL)
                        acc2[mi][ni] = __builtin_amdgcn_mfma_f32_16x16x32_bf16(af[mi], bfr2[ni], acc2[mi][ni], 0, 0, 0);
                }
        }
    };

    if constexpr (PIPE) {
        const int nk = (kend - kbeg) >> 6;
        STAGE(0, kbeg);
        if (nk > 1) STAGE(1, kbeg + 64);
        if (nk > 1) waitvm<LD>(); else waitvm<0>();
        pipe_barrier();
        int cur = 0, stg = 2;
        for (int i = 0; i < nk; ++i) {
            LOAD_A(kbeg + i * 64);                    // issue A regs BEFORE next stage (FIFO-friendly)
            if constexpr (AREG) __builtin_amdgcn_sched_barrier(0);
            if (i + 2 < nk) {
                STAGE(stg, kbeg + (i + 2) * 64);
                stg = (stg == 2) ? 0 : stg + 1;
            }
            COMPUTE(cur);
            cur = (cur == 2) ? 0 : cur + 1;
            if (i + 1 < nk) {
                if (i + 2 < nk) waitvm<LD>();   // leave tile i+2's loads in flight
                else            waitvm<0>();
                pipe_barrier();
            }
        }
    } else {
        int cur = 0;
        STAGE(0, kbeg);
        __syncthreads();
        for (int k0 = kbeg; k0 < kend; k0 += 64) {
            LOAD_A(k0);
            if (k0 + 64 < kend) STAGE(cur ^ 1, k0 + 64);
            COMPUTE(cur);
            __syncthreads();
            cur ^= 1;
        }
    }

    // ---- epilogue ----
    #pragma unroll
    for (int mi = 0; mi < WM; ++mi) {
        #pragma unroll
        for (int ni = 0; ni < NI; ++ni) {
            f32x4 v = acc[mi][ni];
            int col = n0 + wc * (NI * 16) + ni * 16 + r16;
            #pragma unroll
            for (int j = 0; j < 4; ++j) {
                int row = m0 + wr * (WM * 16) + mi * 16 + grp * 4 + j;
                float val = v[j];
                if constexpr (CFG == CFG_PROJ3) {
                    Cout[(size_t)row * LDC + col] = val;
                } else if constexpr (CFG == CFG_WO) {
                    C0[(size_t)row * H + col] = val + X[(size_t)row * H + col];
                } else if constexpr (CFG == CFG_SCORES) {
                    float sv = val * 0.08838834764831845f;   // 1/sqrt(128)
                    if (col > row) sv = -1e30f;
                    Cb[((size_t)hl * S + row) * S + col] = f2bf(sv);
                } else if constexpr (CFG == CFG_PV) {
                    atomAdd(&C0[(size_t)row * 2048 + head * HD + col], val);
                } else if constexpr (CFG == CFG_GATEUP) {
                    if (row < M) {
                        float g = val, u = acc2[mi][ni][j];
                        float a = g / (1.f + expf(-g)) * u;
                        Cb[((size_t)e * S + row) * FFI + col] = f2bf(a);
                    }
                } else { // CFG_DOWN
                    if (row < M) {
                        Cb[((size_t)e * S + row) * H + col] = f2bf(val);
                    }
                }
            }
        }
    }
}

// ---------------------------------------------------------------------------
__global__ __launch_bounds__(256) void rms_h(const float* __restrict__ x,
                                             const float* __restrict__ w,
                                             unsigned short* __restrict__ out)
{
    int row = blockIdx.x, tid = threadIdx.x;
    const float* xr = x + (size_t)row * H;
    float4 a = *(const float4*)&xr[tid * 8];
    float4 b = *(const float4*)&xr[tid * 8 + 4];
    float vals[8] = { a.x, a.y, a.z, a.w, b.x, b.y, b.z, b.w };
    float ss = 0;
    #pragma unroll
    for (int j = 0; j < 8; ++j) ss += vals[j] * vals[j];
    __shared__ float red[4];
    #pragma unroll
    for (int o = 32; o; o >>= 1) ss += __shfl_down(ss, o);
    if ((tid & 63) == 0) red[tid >> 6] = ss;
    __syncthreads();
    float tot = red[0] + red[1] + red[2] + red[3];
    float r = rsqrtf(tot * (1.f / H) + 1e-6f);
    ushortx8 ov;
    #pragma unroll
    for (int j = 0; j < 8; ++j) ov[j] = f2bf(vals[j] * r * w[tid * 8 + j]);
    *(ushortx8*)&out[(size_t)row * H + tid * 8] = ov;
}

__global__ __launch_bounds__(256) void qnorm_rope(const float* __restrict__ qbuf,
                                                  const float* __restrict__ qw,
                                                  const int* __restrict__ pos,
                                                  unsigned short* __restrict__ qatt)
{
    int tok = blockIdx.x, tid = threadIdx.x;
    __shared__ float sh[2048];
    __shared__ float red[4];
    const float* xr = qbuf + (size_t)tok * 2048;
    float4 a = *(const float4*)&xr[tid * 8];
    float4 b = *(const float4*)&xr[tid * 8 + 4];
    *(float4*)&sh[tid * 8] = a;
    *(float4*)&sh[tid * 8 + 4] = b;
    float ss = a.x*a.x + a.y*a.y + a.z*a.z + a.w*a.w + b.x*b.x + b.y*b.y + b.z*b.z + b.w*b.w;
    #pragma unroll
    for (int o = 32; o; o >>= 1) ss += __shfl_down(ss, o);
    if ((tid & 63) == 0) red[tid >> 6] = ss;
    __syncthreads();
    float tot = red[0] + red[1] + red[2] + red[3];
    float r = rsqrtf(tot * (1.f / 2048.f) + 1e-6f);
    float p = (float)pos[tok];
    #pragma unroll
    for (int j = 0; j < 8; ++j) {
        int idx = tid * 8 + j;
        int d = idx & 127, hh = idx >> 7;
        float v = sh[idx] * r * qw[idx];
        float o;
        if (d < 64) {
            int jj = d & 31;
            float ang = p * expf((float)jj * -0.43173470268f);  // ln(1e6)/32
            float c = cosf(ang), sn = sinf(ang);
            if (d < 32) { float v2 = sh[idx + 32] * r * qw[idx + 32]; o = v * c - v2 * sn; }
            else        { float v2 = sh[idx - 32] * r * qw[idx - 32]; o = v * c + v2 * sn; }
        } else o = v;
        qatt[((size_t)hh * S + tok) * HD + d] = f2bf(o);
    }
}

__global__ __launch_bounds__(256) void knorm_rope(const float* __restrict__ kbuf,
                                                  const float* __restrict__ kw,
                                                  const int* __restrict__ pos,
                                                  unsigned short* __restrict__ katt)
{
    int tok = blockIdx.x, tid = threadIdx.x;
    __shared__ float sh[512];
    __shared__ float red[4];
    const float* xr = kbuf + (size_t)tok * 512;
    float2 a = *(const float2*)&xr[tid * 2];
    sh[tid * 2] = a.x; sh[tid * 2 + 1] = a.y;
    float ss = a.x * a.x + a.y * a.y;
    #pragma unroll
    for (int o = 32; o; o >>= 1) ss += __shfl_down(ss, o);
    if ((tid & 63) == 0) red[tid >> 6] = ss;
    __syncthreads();
    float tot = red[0] + red[1] + red[2] + red[3];
    float r = rsqrtf(tot * (1.f / 512.f) + 1e-6f);
    float p = (float)pos[tok];
    #pragma unroll
    for (int j = 0; j < 2; ++j) {
        int idx = tid * 2 + j;
        int d = idx & 127, hh = idx >> 7;
        float v = sh[idx] * r * kw[idx];
        float o;
        if (d < 64) {
            int jj = d & 31;
            float ang = p * expf((float)jj * -0.43173470268f);
            float c = cosf(ang), sn = sinf(ang);
            if (d < 32) { float v2 = sh[idx + 32] * r * kw[idx + 32]; o = v * c - v2 * sn; }
            else        { float v2 = sh[idx - 32] * r * kw[idx - 32]; o = v * c + v2 * sn; }
        } else o = v;
        katt[((size_t)hh * S + tok) * HD + d] = f2bf(o);
    }
}

// in-place row softmax over bf16 scores (16 heads), causal length q+1
__global__ __launch_bounds__(256) void softmax_k(unsigned short* __restrict__ sc)
{
    int bid = blockIdx.x;
    int hl = bid >> 10, q = bid & 1023;
    unsigned short* srow = sc + ((size_t)hl * S + q) * S;
    int L = q + 1, tid = threadIdx.x;
    __shared__ float red[4];
    ushortx4 in4 = *(const ushortx4*)&srow[tid * 4];
    float v[4]; float mx = -3.4e38f;
    #pragma unroll
    for (int i = 0; i < 4; ++i) {
        int j = tid * 4 + i;
        if (j < L) { v[i] = bf2f(in4[i]); mx = fmaxf(mx, v[i]); }
        else v[i] = -3.4e38f;
    }
    float m = mx;
    #pragma unroll
    for (int o = 32; o; o >>= 1) m = fmaxf(m, __shfl_down(m, o));
    if ((tid & 63) == 0) red[tid >> 6] = m;
    __syncthreads();
    float M_ = fmaxf(fmaxf(red[0], red[1]), fmaxf(red[2], red[3]));
    __syncthreads();
    float e[4]; float sum = 0;
    #pragma unroll
    for (int i = 0; i < 4; ++i) {
        int j = tid * 4 + i;
        if (j < L) { e[i] = expf(v[i] - M_); sum += e[i]; } else e[i] = 0.f;
    }
    #pragma unroll
    for (int o = 32; o; o >>= 1) sum += __shfl_down(sum, o);
    if ((tid & 63) == 0) red[tid >> 6] = sum;
    __syncthreads();
    float inv = 1.f / (red[0] + red[1] + red[2] + red[3]);
    ushortx4 o4;
    #pragma unroll
    for (int i = 0; i < 4; ++i) o4[i] = f2bf(e[i] * inv);
    *(ushortx4*)&srow[tid * 4] = o4;
}

__global__ void zero_cnt(int* cnt) { if (threadIdx.x < EXPN) cnt[threadIdx.x] = 0; }

__global__ void zerok(float4* __restrict__ p, int n4)
{
    int i = blockIdx.x * 256 + threadIdx.x;
    if (i < n4) p[i] = float4{0.f, 0.f, 0.f, 0.f};
}

__global__ void cvt_k(const float* __restrict__ src, unsigned short* __restrict__ dst)
{
    int i = blockIdx.x * 256 + threadIdx.x;
    float4 a = *(const float4*)&src[i * 8];
    float4 b = *(const float4*)&src[i * 8 + 4];
    float v[8] = { a.x, a.y, a.z, a.w, b.x, b.y, b.z, b.w };
    ushortx8 o;
    #pragma unroll
    for (int j = 0; j < 8; ++j) o[j] = f2bf(v[j]);
    *(ushortx8*)&dst[i * 8] = o;
}

// router + fused RMSNorm2 output (tbf = norm(res)*ln2w in bf16)
__global__ __launch_bounds__(256) void router_k(const float* __restrict__ res,
                                                const float* __restrict__ ln2w,
                                                const float* __restrict__ rw,
                                                const float* __restrict__ rbias,
                                                int* __restrict__ cnt,
                                                int* __restrict__ tokList,
                                                int* __restrict__ slot,
                                                float* __restrict__ slotw,
                                                unsigned short* __restrict__ tbf)
{
    int tok = blockIdx.x, tid = threadIdx.x;
    const float* xr = res + (size_t)tok * H;
    float4 a = *(const float4*)&xr[tid * 8];
    float4 b = *(const float4*)&xr[tid * 8 + 4];
    float vals[8] = { a.x, a.y, a.z, a.w, b.x, b.y, b.z, b.w };
    float ss = 0;
    #pragma unroll
    for (int j = 0; j < 8; ++j) ss += vals[j] * vals[j];
    __shared__ float red[4];
    float t_ = ss;
    #pragma unroll
    for (int o = 32; o; o >>= 1) t_ += __shfl_down(t_, o);
    if ((tid & 63) == 0) red[tid >> 6] = t_;
    __syncthreads();
    float tot = red[0] + red[1] + red[2] + red[3];
    float r = rsqrtf(tot * (1.f / H) + 1e-6f);

    float acc[EXPN] = {};
    ushortx8 tv8;
    #pragma unroll
    for (int j = 0; j < 8; ++j) {
        float tv = vals[j] * r * ln2w[tid * 8 + j];
        tv8[j] = f2bf(tv);
        const float* rp = rw + (size_t)(tid * 8 + j) * EXPN;
        #pragma unroll
        for (int e = 0; e < EXPN; ++e) acc[e] += tv * rp[e];
    }
    *(ushortx8*)&tbf[(size_t)tok * H + tid * 8] = tv8;
    __shared__ float r8[4][EXPN];
    #pragma unroll
    for (int e = 0; e < EXPN; ++e) {
        float s_ = acc[e];
        #pragma unroll
        for (int o = 32; o; o >>= 1) s_ += __shfl_down(s_, o);
        acc[e] = s_;
    }
    if ((tid & 63) == 0)
        for (int e = 0; e < EXPN; ++e) r8[tid >> 6][e] = acc[e];
    __syncthreads();
    if (tid == 0) {
        float sg[EXPN];
        for (int e = 0; e < EXPN; ++e) {
            float lg = r8[0][e] + r8[1][e] + r8[2][e] + r8[3][e];
            sg[e] = 1.f / (1.f + expf(-lg));
        }
        int i0 = 0; float b0 = -1e30f;
        for (int e = 0; e < EXPN; ++e) {
            float s_ = sg[e] + rbias[e];
            if (s_ > b0) { b0 = s_; i0 = e; }
        }
        int i1 = -1; float b1 = -1e30f;
        for (int e = 0; e < EXPN; ++e) {
            if (e == i0) continue;
            float s_ = sg[e] + rbias[e];
            if (s_ > b1) { b1 = s_; i1 = e; }
        }
        float a0 = sg[i0], a1 = sg[i1], inv = 1.f / (a0 + a1);
        int p0 = atomicAdd(&cnt[i0], 1);
        tokList[i0 * S + p0] = tok;
        int p1 = atomicAdd(&cnt[i1], 1);
        tokList[i1 * S + p1] = tok;
        slot[tok * 2]     = i0 * S + p0;  slotw[tok * 2]     = a0 * inv;
        slot[tok * 2 + 1] = i1 * S + p1;  slotw[tok * 2 + 1] = a1 * inv;
    }
}

// out[t] += w0*eo[slot0] + w1*eo[slot1]
__global__ __launch_bounds__(256) void combine_k(const unsigned short* __restrict__ eo,
                                                 const int* __restrict__ slot,
                                                 const float* __restrict__ slotw,
                                                 float* __restrict__ out)
{
    int t = blockIdx.x;
    int c = threadIdx.x * 8;
    int s0 = slot[t * 2], s1 = slot[t * 2 + 1];
    float w0 = slotw[t * 2], w1 = slotw[t * 2 + 1];
    ushortx8 a = *(const ushortx8*)&eo[(size_t)s0 * H + c];
    ushortx8 b = *(const ushortx8*)&eo[(size_t)s1 * H + c];
    size_t base = (size_t)t * H + c;
    float4 o0 = *(float4*)&out[base];
    float4 o1 = *(float4*)&out[base + 4];
    float ov[8] = { o0.x, o0.y, o0.z, o0.w, o1.x, o1.y, o1.z, o1.w };
    #pragma unroll
    for (int j = 0; j < 8; ++j)
        ov[j] += w0 * bf2f(a[j]) + w1 * bf2f(b[j]);
    *(float4*)&out[base]     = float4{ ov[0], ov[1], ov[2], ov[3] };
    *(float4*)&out[base + 4] = float4{ ov[4], ov[5], ov[6], ov[7] };
}

// ---------------------------------------------------------------------------
extern "C" void kernel_launch(void* const* d_in, const int* in_sizes, int n_in,
                              void* d_out, int out_size, void* d_ws, size_t ws_size,
                              hipStream_t stream)
{
    const float* x     = (const float*)d_in[0];
    const int*   pos   = (const int*)d_in[1];
    const float* ln1w  = (const float*)d_in[2];
    const float* qnw   = (const float*)d_in[3];
    const float* knw   = (const float*)d_in[4];
    const float* wq    = (const float*)d_in[5];
    const float* wk    = (const float*)d_in[6];
    const float* wv    = (const float*)d_in[7];
    const float* wo    = (const float*)d_in[8];
    const float* ln2w  = (const float*)d_in[9];
    const float* rw    = (const float*)d_in[10];
    const float* rbias = (const float*)d_in[11];
    const float* wg    = (const float*)d_in[12];
    const float* wu    = (const float*)d_in[13];
    const float* wd    = (const float*)d_in[14];
    float* out = (float*)d_out;

    char* ws = (char*)d_ws;
    const size_t MB = 1024 * 1024;
    unsigned short* h_bf = (unsigned short*)(ws + 0);          // 4 MB
    float* qbuf  = (float*)(ws + 4 * MB);                      // 8 MB (dead after rope -> ctxf)
    float* ctxf  = (float*)(ws + 4 * MB);                      // 8 MB fp32 (aliases qbuf)
    float* kbuf  = (float*)(ws + 12 * MB);                     // 2 MB
    float* vbuf  = (float*)(ws + 14 * MB);                     // 2 MB
    unsigned short* qatt = (unsigned short*)(ws + 16 * MB);    // 4 MB
    unsigned short* katt = (unsigned short*)(ws + 20 * MB);    // 1 MB
    unsigned short* vT   = (unsigned short*)(ws + 21 * MB);    // 1 MB
    unsigned short* ctx  = (unsigned short*)(ws + 22 * MB);    // 4 MB
    unsigned short* tbf  = (unsigned short*)(ws + 26 * MB);    // 4 MB
    int*   cnt     = (int*)(ws + 30 * MB);                     // 32 B
    int*   tokList = (int*)(ws + 30 * MB + 4096);              // 32 KB
    int*   slot    = (int*)(ws + 30 * MB + 512 * 1024);        // 8 KB
    float* slotw   = (float*)(ws + 30 * MB + 768 * 1024);      // 8 KB
    // attention phase: scores bf16, 16 heads, in-place softmax -> P  [31..63)
    unsigned short* scores = (unsigned short*)(ws + 31 * MB);  // 32 MB
    // MoE phase (aliases attention region):
    unsigned short* act = (unsigned short*)(ws + 31 * MB);     // 16 MB [31..47)
    unsigned short* eo  = (unsigned short*)(ws + 47 * MB);     // 32 MB [47..79)
    // weights bf16 (persistent): [79..195)
    unsigned short* wqT = (unsigned short*)(ws + 79 * MB);     // 8 MB
    unsigned short* wkT = (unsigned short*)(ws + 87 * MB);     // 2 MB
    unsigned short* wvT = (unsigned short*)(ws + 89 * MB);     // 2 MB
    unsigned short* woT = (unsigned short*)(ws + 91 * MB);     // 8 MB
    unsigned short* wgT = (unsigned short*)(ws + 99 * MB);     // 32 MB
    unsigned short* wuT = (unsigned short*)(ws + 131 * MB);    // 32 MB
    unsigned short* wdT = (unsigned short*)(ws + 163 * MB);    // 32 MB -> 195 MB total

    // 0. weight convert+transpose -> bf16 [N][K]
    transT<<<dim3(32, 32, 1), 256, 0, stream>>>(wq, wqT, 2048, 2048);
    transT<<<dim3(8,  32, 1), 256, 0, stream>>>(wk, wkT, 2048, 512);
    transT<<<dim3(8,  32, 1), 256, 0, stream>>>(wv, wvT, 2048, 512);
    transT<<<dim3(32, 32, 1), 256, 0, stream>>>(wo, woT, 2048, 2048);
    transT<<<dim3(16, 32, 8), 256, 0, stream>>>(wg, wgT, 2048, 1024);
    transT<<<dim3(16, 32, 8), 256, 0, stream>>>(wu, wuT, 2048, 1024);
    transT<<<dim3(32, 16, 8), 256, 0, stream>>>(wd, wdT, 1024, 2048);

    // 1. RMSNorm -> h bf16
    rms_h<<<S, 256, 0, stream>>>(x, ln1w, h_bf);

    // 2. fused QKV projection, BN=64, pipelined 3-buffer (768 blocks, 3/CU)
    gemm_k<CFG_PROJ3, 2, 2, true><<<dim3(48, 16, 1), 256, 0, stream>>>(h_bf, wqT, wkT, wvT, qbuf, kbuf, vbuf, nullptr, nullptr, nullptr, nullptr, 0);

    // 3. q/k norm + rope; V transpose (tiled); zero ctxf (qbuf now dead)
    qnorm_rope<<<S, 256, 0, stream>>>(qbuf, qnw, pos, qatt);
    knorm_rope<<<S, 256, 0, stream>>>(kbuf, knw, pos, katt);
    transT<<<dim3(8, 16, 1), 256, 0, stream>>>(vbuf, vT, 1024, 512);
    zerok<<<2048, 256, 0, stream>>>((float4*)ctxf, (8 * MB) / 16);

    // 4. attention, all 16 heads: scores bf16 -> in-place softmax -> PV(BN=64, pipelined, split-K=4)
    gemm_k<CFG_SCORES, 2, 4, false><<<dim3(8, 16, 16), 256, 0, stream>>>(qatt, katt, nullptr, nullptr, nullptr, nullptr, nullptr, scores, nullptr, nullptr, nullptr, 0);
    softmax_k<<<16 * S, 256, 0, stream>>>(scores);
    gemm_k<CFG_PV, 2, 2, true><<<dim3(2, 16, 64), 256, 0, stream>>>(scores, vT, nullptr, nullptr, ctxf, nullptr, nullptr, nullptr, nullptr, nullptr, nullptr, 0);
    cvt_k<<<(S * 2048) / (256 * 8), 256, 0, stream>>>(ctxf, ctx);

    // 5. wo + residual, BN=64, pipelined 3-buffer (512 blocks)
    gemm_k<CFG_WO, 2, 2, true><<<dim3(32, 16, 1), 256, 0, stream>>>(ctx, woT, nullptr, nullptr, out, nullptr, nullptr, nullptr, x, nullptr, nullptr, 0);

    // 6. router (fused RMSNorm2 -> tbf)
    zero_cnt<<<1, 64, 0, stream>>>(cnt);
    router_k<<<S, 256, 0, stream>>>(out, ln2w, rw, rbias, cnt, tokList, slot, slotw, tbf);

    // 7. MoE: gate/up DUAL, A-in-registers, 48 KB 3-buffer pipeline (3/CU) ; down pipelined ; combine
    gemm_k<CFG_GATEUP, 2, 2, true><<<dim3(16, 16, EXPN), 256, 0, stream>>>(tbf, wgT, wuT, nullptr, nullptr, nullptr, nullptr, act, nullptr, cnt, tokList, 0);
    gemm_k<CFG_DOWN, 2, 2, true><<<dim3(32, 16, EXPN), 256, 0, stream>>>(act, wdT, nullptr, nullptr, nullptr, nullptr, nullptr, eo, nullptr, cnt, tokList, 0);
    combine_k<<<S, 256, 0, stream>>>(eo, slot, slotw, out);
}

// Round 18
// 331.426 us; speedup vs baseline: 1.0733x; 1.0733x over previous
//
#include <hip/hip_runtime.h>
#include <hip/hip_bf16.h>
#include <cstdint>

static constexpr int S   = 1024;
static constexpr int H   = 2048;
static constexpr int NH  = 16;
static constexpr int NKV = 4;
static constexpr int HD  = 128;
static constexpr int EXPN = 8;
static constexpr int FFI = 1024;

typedef __bf16 bf16x8 __attribute__((ext_vector_type(8)));
typedef float  f32x4  __attribute__((ext_vector_type(4)));
typedef unsigned short ushortx8 __attribute__((ext_vector_type(8)));
typedef unsigned short ushortx4 __attribute__((ext_vector_type(4)));

#define DEVI __device__ __forceinline__

DEVI unsigned short f2bf(float f) {
    union { float f; uint32_t u; } v; v.f = f;
    uint32_t r = (v.u + 0x7FFFu + ((v.u >> 16) & 1u)) >> 16;
    return (unsigned short)r;
}
DEVI float bf2f(unsigned short s) {
    union { uint32_t u; float f; } v; v.u = ((uint32_t)s) << 16; return v.f;
}

DEVI void atomAdd(float* p, float v) { unsafeAtomicAdd(p, v); }

// async global->LDS, 16B per lane; dest is wave-uniform base + lane*16
DEVI void gll16(const unsigned short* g, unsigned short* l) {
    __builtin_amdgcn_global_load_lds(
        (const __attribute__((address_space(1))) unsigned int*)(g),
        (__attribute__((address_space(3))) unsigned int*)(l),
        16, 0, 0);
}

// counted vmcnt wait (vm only)
template<int N> DEVI void waitvm() {
    if constexpr (N == 0)      asm volatile("s_waitcnt vmcnt(0)" ::: "memory");
    else if constexpr (N == 2) asm volatile("s_waitcnt vmcnt(2)" ::: "memory");
    else if constexpr (N == 4) asm volatile("s_waitcnt vmcnt(4)" ::: "memory");
    else if constexpr (N == 6) asm volatile("s_waitcnt vmcnt(6)" ::: "memory");
    else static_assert(N == 0 || N == 2 || N == 4 || N == 6, "unsupported vmcnt");
}
DEVI void pipe_barrier() {
    __builtin_amdgcn_sched_barrier(0);
    __builtin_amdgcn_s_barrier();
    __builtin_amdgcn_sched_barrier(0);
}

// ---------------------------------------------------------------------------
// Tiled transpose + fp32->bf16 convert:  in fp32 [R][C] -> out bf16 [C][R]
// ---------------------------------------------------------------------------
__global__ __launch_bounds__(256) void transT(const float* __restrict__ in,
                                              unsigned short* __restrict__ outp,
                                              int R, int C)
{
    __shared__ unsigned short tl[64][72];
    int zb = blockIdx.z;
    in   += (size_t)zb * R * C;
    outp += (size_t)zb * R * C;
    int c0 = blockIdx.x * 64, r0 = blockIdx.y * 64;
    int t = threadIdx.x;
    int cq = (t & 15) * 4;
    int rr = t >> 4;
    #pragma unroll
    for (int p = 0; p < 4; ++p) {
        int row = rr + p * 16;
        float4 v = *(const float4*)&in[(size_t)(r0 + row) * C + c0 + cq];
        tl[cq + 0][row] = f2bf(v.x);
        tl[cq + 1][row] = f2bf(v.y);
        tl[cq + 2][row] = f2bf(v.z);
        tl[cq + 3][row] = f2bf(v.w);
    }
    __syncthreads();
    int r8 = (t & 7) * 8;
    int cc = t >> 3;
    #pragma unroll
    for (int p = 0; p < 2; ++p) {
        int col = cc + p * 32;
        ushortx8 v = *(const ushortx8*)&tl[col][r8];
        *(ushortx8*)&outp[(size_t)(c0 + col) * R + r0 + r8] = v;
    }
}

enum { CFG_PROJ3 = 0, CFG_WO = 1, CFG_SCORES = 2, CFG_PV = 3, CFG_GATEUP = 4, CFG_DOWN = 5 };

// ---------------------------------------------------------------------------
// BMxBN MFMA GEMM tile (BM=WM*32, BN=NI*32), 4 waves (2x2), BK=64.
// PIPE=false: 2-buffer LDS + __syncthreads.
// PIPE=true : 3-buffer LDS, 2 tiles in flight, counted vmcnt.
// A bf16 [M][LDA], B bf16 [N][LDBK] (pre-transposed).
// ---------------------------------------------------------------------------
template<int CFG, int WM, int NI, bool PIPE>
__global__ __launch_bounds__(256, 2) void gemm_k(
    const unsigned short* __restrict__ A,
    const unsigned short* __restrict__ B0,
    const unsigned short* __restrict__ B1,
    const unsigned short* __restrict__ B2,
    float* __restrict__ C0,
    float* __restrict__ C1,
    float* __restrict__ C2,
    unsigned short* __restrict__ Cb,
    const float* __restrict__ X,
    const int* __restrict__ cnt,
    const int* __restrict__ tokList,
    int arg0)
{
    constexpr bool DUAL = (CFG == CFG_GATEUP);
    constexpr int BM = WM * 32;
    constexpr int BN = NI * 32;
    constexpr int ASZ = BM * 64;
    constexpr int BSZ = BN * 64;
    constexpr int NBUF = PIPE ? 3 : 2;
    constexpr int LD = WM + NI + (DUAL ? NI : 0);

    const int tid = threadIdx.x;
    const int m0 = blockIdx.y * BM;
    int n0 = blockIdx.x * BN;

    int M = S;
    int kbeg = 0, kend = 0, LDA = 0, LDBK = 0, LDC = 0;
    const unsigned short* Ap = A;
    const unsigned short* Bb = B0;
    const unsigned short* Bb2 = B1;
    const int* tlist = nullptr;
    float* Cout = C0;
    int head = 0, e = 0, hl = 0;

    if constexpr (CFG == CFG_PROJ3) {
        int xt = blockIdx.x;   // BN=64 tiling: q 32 tiles, k 8, v 8
        if (xt < 32)      { Bb = B0; Cout = C0; LDC = 2048; n0 = xt * 64; }
        else if (xt < 40) { Bb = B1; Cout = C1; LDC = 512;  n0 = (xt - 32) * 64; }
        else              { Bb = B2; Cout = C2; LDC = 512;  n0 = (xt - 40) * 64; }
        LDA = H; LDBK = H; kend = H;
    } else if constexpr (CFG == CFG_WO) {
        LDA = H; LDBK = H; LDC = H; kend = H;
    } else if constexpr (CFG == CFG_SCORES) {
        hl = blockIdx.z; head = arg0 + hl;
        if (n0 >= m0 + BM) return;
        Ap = A + (size_t)head * S * HD;
        Bb = B0 + (size_t)(head >> 2) * S * HD;
        kend = HD; LDA = HD; LDBK = HD;
    } else if constexpr (CFG == CFG_PV) {
        int z = blockIdx.z; hl = z >> 2; int ks = z & 3;
        head = arg0 + hl;
        int kcap = m0 + BM;
        kbeg = ks * 256;
        if (kbeg >= kcap) return;
        kend = (kbeg + 256 < kcap) ? kbeg + 256 : kcap;
        Ap = A + (size_t)hl * S * S;
        Bb = B0 + (size_t)(head >> 2) * HD * S;
        LDA = S; LDBK = S;
    } else if constexpr (CFG == CFG_GATEUP) {
        e = blockIdx.z;
        M = cnt[e]; if (m0 >= M) return;
        tlist = tokList + e * S;
        Bb  = B0 + (size_t)e * FFI * H;
        Bb2 = B1 + (size_t)e * FFI * H;
        kend = H; LDA = H; LDBK = H;
    } else { // CFG_DOWN
        e = blockIdx.z;
        M = cnt[e]; if (m0 >= M) return;
        Ap = A + (size_t)e * S * FFI;
        Bb = B0 + (size_t)e * H * FFI;
        kend = FFI; LDA = FFI; LDBK = FFI;
    }

    __shared__ unsigned short As[NBUF * ASZ];
    __shared__ unsigned short Bs[NBUF * BSZ];
    __shared__ unsigned short Bs2[DUAL ? NBUF * BSZ : 8];

    const int lane = tid & 63, grp = lane >> 4, r16 = lane & 15;
    const int wid = tid >> 6, wr = wid >> 1, wc = wid & 1;
    const int wbase8 = (tid & 0xFFC0) * 8;   // wave-uniform LDS short-offset base

    // ---- precompute k-invariant per-thread source offsets (inverse swizzle) ----
    size_t aoff[WM];
    #pragma unroll
    for (int c = 0; c < WM; ++c) {
        int chunk = c * 256 + tid;
        int row = chunk >> 3;
        int kcs = (chunk & 7) * 8;
        int grow = m0 + row;
        if constexpr (CFG == CFG_GATEUP) { int r2 = grow < M ? grow : M - 1; grow = tlist[r2]; }
        else if constexpr (CFG == CFG_DOWN) { grow = grow < M ? grow : M - 1; }
        aoff[c] = (size_t)grow * LDA + (kcs ^ ((row & 7) << 3));
    }
    size_t boff[NI];
    #pragma unroll
    for (int c = 0; c < NI; ++c) {
        int chunk = c * 256 + tid;
        int row = chunk >> 3;
        int kcs = (chunk & 7) * 8;
        boff[c] = (size_t)(n0 + row) * LDBK + (kcs ^ ((row & 7) << 3));
    }

    auto STAGE = [&](int buf, int k0) {
        #pragma unroll
        for (int c = 0; c < WM; ++c)
            gll16(Ap + aoff[c] + k0, &As[buf * ASZ + c * 2048 + wbase8]);
        #pragma unroll
        for (int c = 0; c < NI; ++c)
            gll16(Bb + boff[c] + k0, &Bs[buf * BSZ + c * 2048 + wbase8]);
        if constexpr (DUAL) {
            #pragma unroll
            for (int c = 0; c < NI; ++c)
                gll16(Bb2 + boff[c] + k0, &Bs2[buf * BSZ + c * 2048 + wbase8]);
        }
    };

    f32x4 acc[WM][NI] = {};
    f32x4 acc2[DUAL ? WM : 1][DUAL ? NI : 1] = {};

    auto COMPUTE = [&](int buf) {
        #pragma unroll
        for (int kk = 0; kk < 64; kk += 32) {
            bf16x8 af[WM], bfr[NI], bfr2[DUAL ? NI : 1];
            #pragma unroll
            for (int mi = 0; mi < WM; ++mi) {
                int r = wr * (WM * 16) + mi * 16 + r16;
                int idx = buf * ASZ + r * 64 + ((kk + grp * 8) ^ ((r & 7) << 3));
                af[mi] = __builtin_bit_cast(bf16x8, *(const ushortx8*)&As[idx]);
            }
            #pragma unroll
            for (int ni = 0; ni < NI; ++ni) {
                int r = wc * (NI * 16) + ni * 16 + r16;
                int idx = buf * BSZ + r * 64 + ((kk + grp * 8) ^ ((r & 7) << 3));
                bfr[ni] = __builtin_bit_cast(bf16x8, *(const ushortx8*)&Bs[idx]);
                if constexpr (DUAL)
                    bfr2[ni] = __builtin_bit_cast(bf16x8, *(const ushortx8*)&Bs2[idx]);
            }
            #pragma unroll
            for (int mi = 0; mi < WM; ++mi)
                #pragma unroll
                for (int ni = 0; ni < NI; ++ni) {
                    acc[mi][ni] = __builtin_amdgcn_mfma_f32_16x16x32_bf16(af[mi], bfr[ni], acc[mi][ni], 0, 0, 0);
                    if constexpr (DUAL)
                        acc2[mi][ni] = __builtin_amdgcn_mfma_f32_16x16x32_bf16(af[mi], bfr2[ni], acc2[mi][ni], 0, 0, 0);
                }
        }
    };

    if constexpr (PIPE) {
        const int nk = (kend - kbeg) >> 6;
        STAGE(0, kbeg);
        if (nk > 1) STAGE(1, kbeg + 64);
        if (nk > 1) waitvm<LD>(); else waitvm<0>();
        pipe_barrier();
        int cur = 0, stg = 2;
        for (int i = 0; i < nk; ++i) {
            if (i + 2 < nk) {
                STAGE(stg, kbeg + (i + 2) * 64);
                stg = (stg == 2) ? 0 : stg + 1;
            }
            COMPUTE(cur);
            cur = (cur == 2) ? 0 : cur + 1;
            if (i + 1 < nk) {
                if (i + 2 < nk) waitvm<LD>();   // leave tile i+2's loads in flight
                else            waitvm<0>();
                pipe_barrier();
            }
        }
    } else {
        int cur = 0;
        STAGE(0, kbeg);
        __syncthreads();
        for (int k0 = kbeg; k0 < kend; k0 += 64) {
            if (k0 + 64 < kend) STAGE(cur ^ 1, k0 + 64);
            COMPUTE(cur);
            __syncthreads();
            cur ^= 1;
        }
    }

    // ---- epilogue ----
    #pragma unroll
    for (int mi = 0; mi < WM; ++mi) {
        #pragma unroll
        for (int ni = 0; ni < NI; ++ni) {
            f32x4 v = acc[mi][ni];
            int col = n0 + wc * (NI * 16) + ni * 16 + r16;
            #pragma unroll
            for (int j = 0; j < 4; ++j) {
                int row = m0 + wr * (WM * 16) + mi * 16 + grp * 4 + j;
                float val = v[j];
                if constexpr (CFG == CFG_PROJ3) {
                    Cout[(size_t)row * LDC + col] = val;
                } else if constexpr (CFG == CFG_WO) {
                    C0[(size_t)row * H + col] = val + X[(size_t)row * H + col];
                } else if constexpr (CFG == CFG_SCORES) {
                    float sv = val * 0.08838834764831845f;   // 1/sqrt(128)
                    if (col > row) sv = -1e30f;
                    Cb[((size_t)hl * S + row) * S + col] = f2bf(sv);
                } else if constexpr (CFG == CFG_PV) {
                    atomAdd(&C0[(size_t)row * 2048 + head * HD + col], val);
                } else if constexpr (CFG == CFG_GATEUP) {
                    if (row < M) {
                        float g = val, u = acc2[mi][ni][j];
                        float a = g / (1.f + expf(-g)) * u;
                        Cb[((size_t)e * S + row) * FFI + col] = f2bf(a);
                    }
                } else { // CFG_DOWN
                    if (row < M) {
                        Cb[((size_t)e * S + row) * H + col] = f2bf(val);
                    }
                }
            }
        }
    }
}

// ---------------------------------------------------------------------------
__global__ __launch_bounds__(256) void rms_h(const float* __restrict__ x,
                                             const float* __restrict__ w,
                                             unsigned short* __restrict__ out)
{
    int row = blockIdx.x, tid = threadIdx.x;
    const float* xr = x + (size_t)row * H;
    float4 a = *(const float4*)&xr[tid * 8];
    float4 b = *(const float4*)&xr[tid * 8 + 4];
    float vals[8] = { a.x, a.y, a.z, a.w, b.x, b.y, b.z, b.w };
    float ss = 0;
    #pragma unroll
    for (int j = 0; j < 8; ++j) ss += vals[j] * vals[j];
    __shared__ float red[4];
    #pragma unroll
    for (int o = 32; o; o >>= 1) ss += __shfl_down(ss, o);
    if ((tid & 63) == 0) red[tid >> 6] = ss;
    __syncthreads();
    float tot = red[0] + red[1] + red[2] + red[3];
    float r = rsqrtf(tot * (1.f / H) + 1e-6f);
    ushortx8 ov;
    #pragma unroll
    for (int j = 0; j < 8; ++j) ov[j] = f2bf(vals[j] * r * w[tid * 8 + j]);
    *(ushortx8*)&out[(size_t)row * H + tid * 8] = ov;
}

__global__ __launch_bounds__(256) void qnorm_rope(const float* __restrict__ qbuf,
                                                  const float* __restrict__ qw,
                                                  const int* __restrict__ pos,
                                                  unsigned short* __restrict__ qatt)
{
    int tok = blockIdx.x, tid = threadIdx.x;
    __shared__ float sh[2048];
    __shared__ float red[4];
    const float* xr = qbuf + (size_t)tok * 2048;
    float4 a = *(const float4*)&xr[tid * 8];
    float4 b = *(const float4*)&xr[tid * 8 + 4];
    *(float4*)&sh[tid * 8] = a;
    *(float4*)&sh[tid * 8 + 4] = b;
    float ss = a.x*a.x + a.y*a.y + a.z*a.z + a.w*a.w + b.x*b.x + b.y*b.y + b.z*b.z + b.w*b.w;
    #pragma unroll
    for (int o = 32; o; o >>= 1) ss += __shfl_down(ss, o);
    if ((tid & 63) == 0) red[tid >> 6] = ss;
    __syncthreads();
    float tot = red[0] + red[1] + red[2] + red[3];
    float r = rsqrtf(tot * (1.f / 2048.f) + 1e-6f);
    float p = (float)pos[tok];
    #pragma unroll
    for (int j = 0; j < 8; ++j) {
        int idx = tid * 8 + j;
        int d = idx & 127, hh = idx >> 7;
        float v = sh[idx] * r * qw[idx];
        float o;
        if (d < 64) {
            int jj = d & 31;
            float ang = p * expf((float)jj * -0.43173470268f);  // ln(1e6)/32
            float c = cosf(ang), sn = sinf(ang);
            if (d < 32) { float v2 = sh[idx + 32] * r * qw[idx + 32]; o = v * c - v2 * sn; }
            else        { float v2 = sh[idx - 32] * r * qw[idx - 32]; o = v * c + v2 * sn; }
        } else o = v;
        qatt[((size_t)hh * S + tok) * HD + d] = f2bf(o);
    }
}

__global__ __launch_bounds__(256) void knorm_rope(const float* __restrict__ kbuf,
                                                  const float* __restrict__ kw,
                                                  const int* __restrict__ pos,
                                                  unsigned short* __restrict__ katt)
{
    int tok = blockIdx.x, tid = threadIdx.x;
    __shared__ float sh[512];
    __shared__ float red[4];
    const float* xr = kbuf + (size_t)tok * 512;
    float2 a = *(const float2*)&xr[tid * 2];
    sh[tid * 2] = a.x; sh[tid * 2 + 1] = a.y;
    float ss = a.x * a.x + a.y * a.y;
    #pragma unroll
    for (int o = 32; o; o >>= 1) ss += __shfl_down(ss, o);
    if ((tid & 63) == 0) red[tid >> 6] = ss;
    __syncthreads();
    float tot = red[0] + red[1] + red[2] + red[3];
    float r = rsqrtf(tot * (1.f / 512.f) + 1e-6f);
    float p = (float)pos[tok];
    #pragma unroll
    for (int j = 0; j < 2; ++j) {
        int idx = tid * 2 + j;
        int d = idx & 127, hh = idx >> 7;
        float v = sh[idx] * r * kw[idx];
        float o;
        if (d < 64) {
            int jj = d & 31;
            float ang = p * expf((float)jj * -0.43173470268f);
            float c = cosf(ang), sn = sinf(ang);
            if (d < 32) { float v2 = sh[idx + 32] * r * kw[idx + 32]; o = v * c - v2 * sn; }
            else        { float v2 = sh[idx - 32] * r * kw[idx - 32]; o = v * c + v2 * sn; }
        } else o = v;
        katt[((size_t)hh * S + tok) * HD + d] = f2bf(o);
    }
}

// in-place row softmax over bf16 scores (16 heads), causal length q+1
__global__ __launch_bounds__(256) void softmax_k(unsigned short* __restrict__ sc)
{
    int bid = blockIdx.x;
    int hl = bid >> 10, q = bid & 1023;
    unsigned short* srow = sc + ((size_t)hl * S + q) * S;
    int L = q + 1, tid = threadIdx.x;
    __shared__ float red[4];
    ushortx4 in4 = *(const ushortx4*)&srow[tid * 4];
    float v[4]; float mx = -3.4e38f;
    #pragma unroll
    for (int i = 0; i < 4; ++i) {
        int j = tid * 4 + i;
        if (j < L) { v[i] = bf2f(in4[i]); mx = fmaxf(mx, v[i]); }
        else v[i] = -3.4e38f;
    }
    float m = mx;
    #pragma unroll
    for (int o = 32; o; o >>= 1) m = fmaxf(m, __shfl_down(m, o));
    if ((tid & 63) == 0) red[tid >> 6] = m;
    __syncthreads();
    float M_ = fmaxf(fmaxf(red[0], red[1]), fmaxf(red[2], red[3]));
    __syncthreads();
    float e[4]; float sum = 0;
    #pragma unroll
    for (int i = 0; i < 4; ++i) {
        int j = tid * 4 + i;
        if (j < L) { e[i] = expf(v[i] - M_); sum += e[i]; } else e[i] = 0.f;
    }
    #pragma unroll
    for (int o = 32; o; o >>= 1) sum += __shfl_down(sum, o);
    if ((tid & 63) == 0) red[tid >> 6] = sum;
    __syncthreads();
    float inv = 1.f / (red[0] + red[1] + red[2] + red[3]);
    ushortx4 o4;
    #pragma unroll
    for (int i = 0; i < 4; ++i) o4[i] = f2bf(e[i] * inv);
    *(ushortx4*)&srow[tid * 4] = o4;
}

__global__ void zero_cnt(int* cnt) { if (threadIdx.x < EXPN) cnt[threadIdx.x] = 0; }

__global__ void zerok(float4* __restrict__ p, int n4)
{
    int i = blockIdx.x * 256 + threadIdx.x;
    if (i < n4) p[i] = float4{0.f, 0.f, 0.f, 0.f};
}

__global__ void cvt_k(const float* __restrict__ src, unsigned short* __restrict__ dst)
{
    int i = blockIdx.x * 256 + threadIdx.x;
    float4 a = *(const float4*)&src[i * 8];
    float4 b = *(const float4*)&src[i * 8 + 4];
    float v[8] = { a.x, a.y, a.z, a.w, b.x, b.y, b.z, b.w };
    ushortx8 o;
    #pragma unroll
    for (int j = 0; j < 8; ++j) o[j] = f2bf(v[j]);
    *(ushortx8*)&dst[i * 8] = o;
}

// router + fused RMSNorm2 output (tbf = norm(res)*ln2w in bf16)
__global__ __launch_bounds__(256) void router_k(const float* __restrict__ res,
                                                const float* __restrict__ ln2w,
                                                const float* __restrict__ rw,
                                                const float* __restrict__ rbias,
                                                int* __restrict__ cnt,
                                                int* __restrict__ tokList,
                                                int* __restrict__ slot,
                                                float* __restrict__ slotw,
                                                unsigned short* __restrict__ tbf)
{
    int tok = blockIdx.x, tid = threadIdx.x;
    const float* xr = res + (size_t)tok * H;
    float4 a = *(const float4*)&xr[tid * 8];
    float4 b = *(const float4*)&xr[tid * 8 + 4];
    float vals[8] = { a.x, a.y, a.z, a.w, b.x, b.y, b.z, b.w };
    float ss = 0;
    #pragma unroll
    for (int j = 0; j < 8; ++j) ss += vals[j] * vals[j];
    __shared__ float red[4];
    float t_ = ss;
    #pragma unroll
    for (int o = 32; o; o >>= 1) t_ += __shfl_down(t_, o);
    if ((tid & 63) == 0) red[tid >> 6] = t_;
    __syncthreads();
    float tot = red[0] + red[1] + red[2] + red[3];
    float r = rsqrtf(tot * (1.f / H) + 1e-6f);

    float acc[EXPN] = {};
    ushortx8 tv8;
    #pragma unroll
    for (int j = 0; j < 8; ++j) {
        float tv = vals[j] * r * ln2w[tid * 8 + j];
        tv8[j] = f2bf(tv);
        const float* rp = rw + (size_t)(tid * 8 + j) * EXPN;
        #pragma unroll
        for (int e = 0; e < EXPN; ++e) acc[e] += tv * rp[e];
    }
    *(ushortx8*)&tbf[(size_t)tok * H + tid * 8] = tv8;
    __shared__ float r8[4][EXPN];
    #pragma unroll
    for (int e = 0; e < EXPN; ++e) {
        float s_ = acc[e];
        #pragma unroll
        for (int o = 32; o; o >>= 1) s_ += __shfl_down(s_, o);
        acc[e] = s_;
    }
    if ((tid & 63) == 0)
        for (int e = 0; e < EXPN; ++e) r8[tid >> 6][e] = acc[e];
    __syncthreads();
    if (tid == 0) {
        float sg[EXPN];
        for (int e = 0; e < EXPN; ++e) {
            float lg = r8[0][e] + r8[1][e] + r8[2][e] + r8[3][e];
            sg[e] = 1.f / (1.f + expf(-lg));
        }
        int i0 = 0; float b0 = -1e30f;
        for (int e = 0; e < EXPN; ++e) {
            float s_ = sg[e] + rbias[e];
            if (s_ > b0) { b0 = s_; i0 = e; }
        }
        int i1 = -1; float b1 = -1e30f;
        for (int e = 0; e < EXPN; ++e) {
            if (e == i0) continue;
            float s_ = sg[e] + rbias[e];
            if (s_ > b1) { b1 = s_; i1 = e; }
        }
        float a0 = sg[i0], a1 = sg[i1], inv = 1.f / (a0 + a1);
        int p0 = atomicAdd(&cnt[i0], 1);
        tokList[i0 * S + p0] = tok;
        int p1 = atomicAdd(&cnt[i1], 1);
        tokList[i1 * S + p1] = tok;
        slot[tok * 2]     = i0 * S + p0;  slotw[tok * 2]     = a0 * inv;
        slot[tok * 2 + 1] = i1 * S + p1;  slotw[tok * 2 + 1] = a1 * inv;
    }
}

// out[t] += w0*eo[slot0] + w1*eo[slot1]
__global__ __launch_bounds__(256) void combine_k(const unsigned short* __restrict__ eo,
                                                 const int* __restrict__ slot,
                                                 const float* __restrict__ slotw,
                                                 float* __restrict__ out)
{
    int t = blockIdx.x;
    int c = threadIdx.x * 8;
    int s0 = slot[t * 2], s1 = slot[t * 2 + 1];
    float w0 = slotw[t * 2], w1 = slotw[t * 2 + 1];
    ushortx8 a = *(const ushortx8*)&eo[(size_t)s0 * H + c];
    ushortx8 b = *(const ushortx8*)&eo[(size_t)s1 * H + c];
    size_t base = (size_t)t * H + c;
    float4 o0 = *(float4*)&out[base];
    float4 o1 = *(float4*)&out[base + 4];
    float ov[8] = { o0.x, o0.y, o0.z, o0.w, o1.x, o1.y, o1.z, o1.w };
    #pragma unroll
    for (int j = 0; j < 8; ++j)
        ov[j] += w0 * bf2f(a[j]) + w1 * bf2f(b[j]);
    *(float4*)&out[base]     = float4{ ov[0], ov[1], ov[2], ov[3] };
    *(float4*)&out[base + 4] = float4{ ov[4], ov[5], ov[6], ov[7] };
}

// ---------------------------------------------------------------------------
extern "C" void kernel_launch(void* const* d_in, const int* in_sizes, int n_in,
                              void* d_out, int out_size, void* d_ws, size_t ws_size,
                              hipStream_t stream)
{
    const float* x     = (const float*)d_in[0];
    const int*   pos   = (const int*)d_in[1];
    const float* ln1w  = (const float*)d_in[2];
    const float* qnw   = (const float*)d_in[3];
    const float* knw   = (const float*)d_in[4];
    const float* wq    = (const float*)d_in[5];
    const float* wk    = (const float*)d_in[6];
    const float* wv    = (const float*)d_in[7];
    const float* wo    = (const float*)d_in[8];
    const float* ln2w  = (const float*)d_in[9];
    const float* rw    = (const float*)d_in[10];
    const float* rbias = (const float*)d_in[11];
    const float* wg    = (const float*)d_in[12];
    const float* wu    = (const float*)d_in[13];
    const float* wd    = (const float*)d_in[14];
    float* out = (float*)d_out;

    char* ws = (char*)d_ws;
    const size_t MB = 1024 * 1024;
    unsigned short* h_bf = (unsigned short*)(ws + 0);          // 4 MB
    float* qbuf  = (float*)(ws + 4 * MB);                      // 8 MB (dead after rope -> ctxf)
    float* ctxf  = (float*)(ws + 4 * MB);                      // 8 MB fp32 (aliases qbuf)
    float* kbuf  = (float*)(ws + 12 * MB);                     // 2 MB
    float* vbuf  = (float*)(ws + 14 * MB);                     // 2 MB
    unsigned short* qatt = (unsigned short*)(ws + 16 * MB);    // 4 MB
    unsigned short* katt = (unsigned short*)(ws + 20 * MB);    // 1 MB
    unsigned short* vT   = (unsigned short*)(ws + 21 * MB);    // 1 MB
    unsigned short* ctx  = (unsigned short*)(ws + 22 * MB);    // 4 MB
    unsigned short* tbf  = (unsigned short*)(ws + 26 * MB);    // 4 MB
    int*   cnt     = (int*)(ws + 30 * MB);                     // 32 B
    int*   tokList = (int*)(ws + 30 * MB + 4096);              // 32 KB
    int*   slot    = (int*)(ws + 30 * MB + 512 * 1024);        // 8 KB
    float* slotw   = (float*)(ws + 30 * MB + 768 * 1024);      // 8 KB
    // attention phase: scores bf16, 16 heads, in-place softmax -> P  [31..63)
    unsigned short* scores = (unsigned short*)(ws + 31 * MB);  // 32 MB
    // MoE phase (aliases attention region):
    unsigned short* act = (unsigned short*)(ws + 31 * MB);     // 16 MB [31..47)
    unsigned short* eo  = (unsigned short*)(ws + 47 * MB);     // 32 MB [47..79)
    // weights bf16 (persistent): [79..195)
    unsigned short* wqT = (unsigned short*)(ws + 79 * MB);     // 8 MB
    unsigned short* wkT = (unsigned short*)(ws + 87 * MB);     // 2 MB
    unsigned short* wvT = (unsigned short*)(ws + 89 * MB);     // 2 MB
    unsigned short* woT = (unsigned short*)(ws + 91 * MB);     // 8 MB
    unsigned short* wgT = (unsigned short*)(ws + 99 * MB);     // 32 MB
    unsigned short* wuT = (unsigned short*)(ws + 131 * MB);    // 32 MB
    unsigned short* wdT = (unsigned short*)(ws + 163 * MB);    // 32 MB -> 195 MB total

    // 0. weight convert+transpose -> bf16 [N][K]
    transT<<<dim3(32, 32, 1), 256, 0, stream>>>(wq, wqT, 2048, 2048);
    transT<<<dim3(8,  32, 1), 256, 0, stream>>>(wk, wkT, 2048, 512);
    transT<<<dim3(8,  32, 1), 256, 0, stream>>>(wv, wvT, 2048, 512);
    transT<<<dim3(32, 32, 1), 256, 0, stream>>>(wo, woT, 2048, 2048);
    transT<<<dim3(16, 32, 8), 256, 0, stream>>>(wg, wgT, 2048, 1024);
    transT<<<dim3(16, 32, 8), 256, 0, stream>>>(wu, wuT, 2048, 1024);
    transT<<<dim3(32, 16, 8), 256, 0, stream>>>(wd, wdT, 1024, 2048);

    // 1. RMSNorm -> h bf16
    rms_h<<<S, 256, 0, stream>>>(x, ln1w, h_bf);

    // 2. fused QKV projection, BN=64, pipelined 3-buffer (768 blocks, 3/CU)
    gemm_k<CFG_PROJ3, 2, 2, true><<<dim3(48, 16, 1), 256, 0, stream>>>(h_bf, wqT, wkT, wvT, qbuf, kbuf, vbuf, nullptr, nullptr, nullptr, nullptr, 0);

    // 3. q/k norm + rope; V transpose (tiled); zero ctxf (qbuf now dead)
    qnorm_rope<<<S, 256, 0, stream>>>(qbuf, qnw, pos, qatt);
    knorm_rope<<<S, 256, 0, stream>>>(kbuf, knw, pos, katt);
    transT<<<dim3(8, 16, 1), 256, 0, stream>>>(vbuf, vT, 1024, 512);
    zerok<<<2048, 256, 0, stream>>>((float4*)ctxf, (8 * MB) / 16);

    // 4. attention, all 16 heads: scores bf16 -> in-place softmax -> PV(BN=64, pipelined, split-K=4)
    gemm_k<CFG_SCORES, 2, 4, false><<<dim3(8, 16, 16), 256, 0, stream>>>(qatt, katt, nullptr, nullptr, nullptr, nullptr, nullptr, scores, nullptr, nullptr, nullptr, 0);
    softmax_k<<<16 * S, 256, 0, stream>>>(scores);
    gemm_k<CFG_PV, 2, 2, true><<<dim3(2, 16, 64), 256, 0, stream>>>(scores, vT, nullptr, nullptr, ctxf, nullptr, nullptr, nullptr, nullptr, nullptr, nullptr, 0);
    cvt_k<<<(S * 2048) / (256 * 8), 256, 0, stream>>>(ctxf, ctx);

    // 5. wo + residual, BN=64, pipelined 3-buffer (512 blocks)
    gemm_k<CFG_WO, 2, 2, true><<<dim3(32, 16, 1), 256, 0, stream>>>(ctx, woT, nullptr, nullptr, out, nullptr, nullptr, nullptr, x, nullptr, nullptr, 0);

    // 6. router (fused RMSNorm2 -> tbf)
    zero_cnt<<<1, 64, 0, stream>>>(cnt);
    router_k<<<S, 256, 0, stream>>>(out, ln2w, rw, rbias, cnt, tokList, slot, slotw, tbf);

    // 7. MoE: gate/up BM=64/BN=64 DUAL 2-buffer fused silu -> act ; down BN=64 pipelined -> eo ; combine
    gemm_k<CFG_GATEUP, 2, 2, false><<<dim3(16, 16, EXPN), 256, 0, stream>>>(tbf, wgT, wuT, nullptr, nullptr, nullptr, nullptr, act, nullptr, cnt, tokList, 0);
    gemm_k<CFG_DOWN, 2, 2, true><<<dim3(32, 16, EXPN), 256, 0, stream>>>(act, wdT, nullptr, nullptr, nullptr, nullptr, nullptr, eo, nullptr, cnt, tokList, 0);
    combine_k<<<S, 256, 0, stream>>>(eo, slot, slotw, out);
}